// Round 14
// baseline (279.537 us; speedup 1.0000x reference)
//
#include <hip/hip_runtime.h>
#include <hip/hip_bf16.h>

// DiagWinAttention: nw=4096, N=64 tokens, E=96 = 6 heads x 16. fp32 I/O.
// R14: barrier-free decomposition. 1 wave (64 threads) = 1 whole window:
// loop over 6 heads (registers recycled per head), LN with lane=row (no
// cross-wave reduce), proj from 24 in-reg Xn fragments, 32-row fp32 Y overlay
// + coalesced copy. ZERO __syncthreads; only wave-local lgkmcnt waits.
// 13.1KB LDS -> 12 independent blocks/CU; waves at different phases
// co-schedule (convoy effect of 6-wave barrier-coupled blocks eliminated).
// R11 lesson kept: output staged through LDS (direct scattered stores
// diverged post-timing). Tripwire: WRITE_SIZE == 98304.

typedef short v4s __attribute__((ext_vector_type(4)));
typedef float v4f __attribute__((ext_vector_type(4)));

#define MFMA16(A, B, C) __builtin_amdgcn_mfma_f32_16x16x16bf16_1k(A, B, C, 0, 0, 0)

static __device__ __forceinline__ ushort f2b(float x) {
  union { __hip_bfloat16 h; ushort u; } c; c.h = __float2bfloat16(x); return c.u;
}
static __device__ __forceinline__ float b2f(ushort u) {
  union { ushort u; __hip_bfloat16 h; } c; c.u = u; return __bfloat162float(c.h);
}

#define SXS 102     // X row stride (bf16 units); 51 dwords -> odd dword stride,
                    // conflict-free b64 column reads. Also fp32 Y stride.
#define LOG2E 1.4426950408889634f
#define WAVE_SYNC() asm volatile("s_waitcnt lgkmcnt(0)" ::: "memory")

__global__ __launch_bounds__(64, 3)
void winattn_kernel(const float* __restrict__ gQ, const float* __restrict__ gK,
                    const float* __restrict__ gV, const float* __restrict__ gM,
                    const float* __restrict__ gBT, const float* __restrict__ gGa,
                    const float* __restrict__ gBe, const float* __restrict__ gW,
                    const float* __restrict__ gPb, float* __restrict__ gO)
{
  __shared__ __align__(16) ushort sX[64 * SXS];   // 13056 B; X -> Xn -> fp32 Y half

  const int lane = threadIdx.x;      // 0..63
  const int l15  = lane & 15;
  const int g    = lane >> 4;
  const int w    = blockIdx.x;
  const size_t base = (size_t)w * 6144;
  const float4* m4f = (const float4*)(gM + (size_t)w * 4096);

  // ================= attention, one head at a time (registers recycled) ====
  #pragma unroll 1
  for (int h = 0; h < 6; ++h) {
    // Q,K fragments (A-operand rows), scale*log2e folded into Q
    v4s aq[4], bk[4];
    {
      const float QS = 0.25f * LOG2E;
      const float* qp = gQ + base + 16 * h + 4 * g;
      const float* kp = gK + base + 16 * h + 4 * g;
      #pragma unroll
      for (int t = 0; t < 4; ++t) {
        float4 qv = *(const float4*)(qp + (16 * t + l15) * 96);
        float4 kv = *(const float4*)(kp + (16 * t + l15) * 96);
        v4s a; a[0] = (short)f2b(qv.x * QS); a[1] = (short)f2b(qv.y * QS);
        a[2] = (short)f2b(qv.z * QS); a[3] = (short)f2b(qv.w * QS);
        aq[t] = a;
        v4s b; b[0] = (short)f2b(kv.x); b[1] = (short)f2b(kv.y);
        b[2] = (short)f2b(kv.z); b[3] = (short)f2b(kv.w);
        bk[t] = b;
      }
    }
    // V fragments (B-operand)
    v4s vf[4];
    {
      const float* vp = gV + base + 16 * h + l15;
      #pragma unroll
      for (int kk = 0; kk < 4; ++kk) {
        float a0 = vp[(16 * kk + 4 * g + 0) * 96];
        float a1 = vp[(16 * kk + 4 * g + 1) * 96];
        float a2 = vp[(16 * kk + 4 * g + 2) * 96];
        float a3 = vp[(16 * kk + 4 * g + 3) * 96];
        v4s t; t[0] = (short)f2b(a0); t[1] = (short)f2b(a1);
        t[2] = (short)f2b(a2); t[3] = (short)f2b(a3);
        vf[kk] = t;
      }
    }
    // rel-pos bias for this head: 28 scalar loads (5.4KB table, L1/L2-hot)
    float bv[7][4];
    {
      const int bb = ((l15 >> 3) - (g >> 1)) * 15 + (l15 & 7) - 4 * (g & 1) + 112;
      #pragma unroll
      for (int d = 0; d < 7; ++d)
        #pragma unroll
        for (int rg = 0; rg < 4; ++rg)
          bv[d][rg] = gBT[(bb + 30 * (d - 3) - rg) * 6 + h] * LOG2E;
    }
    const float* qr = gQ + base + 16 * h + l15;   // residual column

    #pragma unroll
    for (int rt = 0; rt < 4; ++rt) {
      float4 mv[4];
      #pragma unroll
      for (int ct = 0; ct < 4; ++ct)
        mv[ct] = m4f[(16 * rt + l15) * 16 + 4 * ct + g];

      float s = 0.f;
      v4s pa[4];
      #pragma unroll
      for (int ct = 0; ct < 4; ++ct) {
        const float* bd = bv[rt - ct + 3];
        v4f acc = {mv[ct].x * LOG2E + bd[0], mv[ct].y * LOG2E + bd[1],
                   mv[ct].z * LOG2E + bd[2], mv[ct].w * LOG2E + bd[3]};
        acc = MFMA16(bk[ct], aq[rt], acc);
        float e0 = exp2f(acc[0]);
        float e1 = exp2f(acc[1]);
        float e2 = exp2f(acc[2]);
        float e3 = exp2f(acc[3]);
        s += (e0 + e1) + (e2 + e3);
        v4s t;
        t[0] = (short)f2b(e0); t[1] = (short)f2b(e1);
        t[2] = (short)f2b(e2); t[3] = (short)f2b(e3);
        pa[ct] = t;
      }
      s += __shfl_xor(s, 16, 64);
      s += __shfl_xor(s, 32, 64);
      const float r = __builtin_amdgcn_rcpf(s);   // full row sum, row 16rt+l15

      v4f oa = {0.f, 0.f, 0.f, 0.f};
      #pragma unroll
      for (int ct = 0; ct < 4; ++ct) oa = MFMA16(pa[ct], vf[ct], oa);

      // O row = 16rt+4g+rg needs r from lane l15 == 4g+rg
      #pragma unroll
      for (int rg = 0; rg < 4; ++rg) {
        const float rr = __shfl(r, 4 * g + rg, 64);
        const int row = 16 * rt + 4 * g + rg;
        sX[row * SXS + 16 * h + l15] = f2b(oa[rg] * rr + 0.25f * qr[row * 96]);
      }
    }
  }
  WAVE_SYNC();                                   // X writes visible wave-locally

  // ================= LayerNorm: lane = row (no cross-wave reduce) ==========
  {
    const ushort4* xr = (const ushort4*)&sX[lane * SXS];
    float s1 = 0.f, s2 = 0.f;
    #pragma unroll
    for (int i = 0; i < 24; ++i) {
      ushort4 u = xr[i];
      float x0 = b2f(u.x), x1 = b2f(u.y), x2 = b2f(u.z), x3 = b2f(u.w);
      s1 += x0 + x1 + x2 + x3;
      s2 += x0 * x0 + x1 * x1 + x2 * x2 + x3 * x3;
    }
    const float mu  = s1 * (1.f / 96.f);
    const float var = s2 * (1.f / 96.f) - mu * mu;
    const float rsig = __builtin_amdgcn_rsqf(var + 1e-5f);
    const float4* g4 = (const float4*)gGa;       // wave-uniform -> s_loads
    const float4* b4 = (const float4*)gBe;
    ushort4* xw = (ushort4*)&sX[lane * SXS];
    #pragma unroll
    for (int i = 0; i < 24; ++i) {
      ushort4 u = xw[i];
      float4 gv = g4[i], bvv = b4[i];
      ushort4 o;
      o.x = f2b((b2f(u.x) - mu) * rsig * gv.x + bvv.x);
      o.y = f2b((b2f(u.y) - mu) * rsig * gv.y + bvv.y);
      o.z = f2b((b2f(u.z) - mu) * rsig * gv.z + bvv.z);
      o.w = f2b((b2f(u.w) - mu) * rsig * gv.w + bvv.w);
      xw[i] = o;
    }
  }
  WAVE_SYNC();                                   // Xn visible wave-locally

  // ================= Xn fully into registers (sX then dead) ================
  v4s xa[4][6];
  #pragma unroll
  for (int mt = 0; mt < 4; ++mt)
    #pragma unroll
    for (int kk = 0; kk < 6; ++kk)
      xa[mt][kk] = *(const v4s*)&sX[(16 * mt + l15) * SXS + 16 * kk + 4 * g];
  WAVE_SYNC();                                   // reads done before Y overlay

  // ================= projection + staged output, two 32-row halves =========
  float* sY = (float*)sX;                        // 32 x SXS fp32 = 13056 B
  float4* o4 = (float4*)(gO + base);
  #pragma unroll
  for (int half = 0; half < 2; ++half) {
    #pragma unroll
    for (int st = 0; st < 6; ++st) {
      const int oc = 16 * st + l15;
      v4s wfr[6];
      #pragma unroll
      for (int kk = 0; kk < 6; ++kk) {
        float4 wv = *(const float4*)(gW + oc * 96 + kk * 16 + 4 * g);
        v4s t; t[0] = (short)f2b(wv.x); t[1] = (short)f2b(wv.y);
        t[2] = (short)f2b(wv.z); t[3] = (short)f2b(wv.w);
        wfr[kk] = t;
      }
      const float pb = gPb[oc];
      #pragma unroll
      for (int m2 = 0; m2 < 2; ++m2) {
        const int mt = 2 * half + m2;
        v4f ya = {0.f, 0.f, 0.f, 0.f};
        #pragma unroll
        for (int kk = 0; kk < 6; ++kk) ya = MFMA16(xa[mt][kk], wfr[kk], ya);
        #pragma unroll
        for (int rg = 0; rg < 4; ++rg)
          sY[(16 * m2 + 4 * g + rg) * SXS + oc] = ya[rg] + pb;
      }
    }
    WAVE_SYNC();                                 // Y scatter done
    #pragma unroll
    for (int i = 0; i < 12; ++i) {
      const int idx = lane + 64 * i;             // 768 float4 = 32 rows x 24
      const int r = idx / 24, c = idx % 24;
      o4[half * 768 + idx] = *(const float4*)&sY[r * SXS + c * 4];
    }
    WAVE_SYNC();                                 // copy reads done before reuse
  }
}

extern "C" void kernel_launch(void* const* d_in, const int* in_sizes, int n_in,
                              void* d_out, int out_size, void* d_ws, size_t ws_size,
                              hipStream_t stream) {
  (void)in_sizes; (void)n_in; (void)out_size; (void)d_ws; (void)ws_size;
  winattn_kernel<<<dim3(4096), dim3(64), 0, stream>>>(
      (const float*)d_in[0], (const float*)d_in[1], (const float*)d_in[2],
      (const float*)d_in[3], (const float*)d_in[4], (const float*)d_in[5],
      (const float*)d_in[6], (const float*)d_in[7], (const float*)d_in[8],
      (float*)d_out);
}

// Round 15
// 271.027 us; speedup vs baseline: 1.0314x; 1.0314x over previous
//
#include <hip/hip_runtime.h>
#include <hip/hip_bf16.h>

// DiagWinAttention: nw=4096, N=64 tokens, E=96 = 6 heads x 16. fp32 I/O.
// R15 = R9 body (best passing: 138.6us, 44 VGPR, no spill) wrapped as
// PERSISTENT blocks: grid 1280 = 5 blocks/CU (the static LDS/wave limit),
// each looping over ~3-4 windows. Steady-state residency = static (30
// waves/CU) instead of the ~1.7-blocks/CU average caused by block churn.
// Loop adds no per-window register state (R6 lesson: prefetch state spills).
// sB (bias) staged once pre-loop; sM restaged per window behind barriers.
// R11 lesson: output staged through LDS. Tripwire: WRITE_SIZE == 98304.

typedef short v4s __attribute__((ext_vector_type(4)));
typedef float v4f __attribute__((ext_vector_type(4)));

#define MFMA16(A, B, C) __builtin_amdgcn_mfma_f32_16x16x16bf16_1k(A, B, C, 0, 0, 0)

static __device__ __forceinline__ ushort f2b(float x) {
  union { __hip_bfloat16 h; ushort u; } c; c.h = __float2bfloat16(x); return c.u;
}
static __device__ __forceinline__ float b2f(ushort u) {
  union { ushort u; __hip_bfloat16 h; } c; c.u = u; return __bfloat162float(c.h);
}

#define SMS 68      // mask LDS row stride (bf16)
#define SXS 100     // X row stride (bf16)
#define SBS 228     // bias table per-head stride (fp32)
#define LOG2E 1.4426950408889634f
#define NW   4096
#define GRID 1280   // 5 blocks/CU x 256 CUs

__global__ __launch_bounds__(384, 5)
void winattn_kernel(const float* __restrict__ gQ, const float* __restrict__ gK,
                    const float* __restrict__ gV, const float* __restrict__ gM,
                    const float* __restrict__ gBT, const float* __restrict__ gGa,
                    const float* __restrict__ gBe, const float* __restrict__ gW,
                    const float* __restrict__ gPb, float* __restrict__ gO)
{
  __shared__ __align__(16) ushort sM[64 * SMS];  //  8704 B mask * log2e (bf16)
  __shared__ __align__(16) ushort sX[64 * SXS];  // 12800 B X -> Xn -> fp32 Y
  __shared__ float sB[6 * SBS];                  //  5472 B bias tables * log2e
  __shared__ float sPS[64 * 13];                 //  3328 B LN partials
  // total 30304 B -> 5 blocks/CU

  const int tid  = threadIdx.x;
  const int wave = tid >> 6;         // head
  const int lane = tid & 63;
  const int l15  = lane & 15;
  const int g    = lane >> 4;

  // ---- bias table -> LDS once (window-invariant) ----
  for (int i = tid; i < 1350; i += 384) {
    const int idx = i / 6, h = i - 6 * idx;
    sB[h * SBS + idx] = gBT[i] * LOG2E;
  }
  const float* bh = &sB[wave * SBS];
  const int bb = ((l15 >> 3) - (g >> 1)) * 15 + (l15 & 7) - 4 * (g & 1) + 112;
  const int oc = 16 * wave + l15;
  const int r0 = tid / 24, c0 = tid % 24;        // output copy indices

  #pragma unroll 1
  for (int w = blockIdx.x; w < NW; w += GRID) {
    const size_t base = (size_t)w * 6144;

    // ---- mask -> LDS (bf16, * log2e) ----
    {
      const float4* m4 = (const float4*)(gM + (size_t)w * 4096);
      #pragma unroll
      for (int i = 0; i < 3; ++i) {
        const int idx = tid + i * 384;
        if (idx < 1024) {
          const int r = idx >> 4, cc = (idx & 15) * 4;
          float4 a = m4[idx];
          ushort4 u;
          u.x = f2b(a.x * LOG2E); u.y = f2b(a.y * LOG2E);
          u.z = f2b(a.z * LOG2E); u.w = f2b(a.w * LOG2E);
          *(ushort4*)&sM[r * SMS + cc] = u;
        }
      }
    }

    // ---- V fragments (B-operand): vf[kk] reg j = V[16kk+4g+j][16*wave+l15] ----
    v4s vf[4];
    {
      const float* vp = gV + base + 16 * wave + l15;
      #pragma unroll
      for (int kk = 0; kk < 4; ++kk) {
        float a0 = vp[(16 * kk + 4 * g + 0) * 96];
        float a1 = vp[(16 * kk + 4 * g + 1) * 96];
        float a2 = vp[(16 * kk + 4 * g + 2) * 96];
        float a3 = vp[(16 * kk + 4 * g + 3) * 96];
        v4s t; t[0] = (short)f2b(a0); t[1] = (short)f2b(a1);
        t[2] = (short)f2b(a2); t[3] = (short)f2b(a3);
        vf[kk] = t;
      }
    }

    // ---- Q,K fragments direct from global (A-operand rows) ----
    v4s aq[4], bk[4];
    {
      const float QS = 0.25f * LOG2E;            // scale * log2e folded into Q
      const float* qp = gQ + base + 16 * wave + 4 * g;
      const float* kp = gK + base + 16 * wave + 4 * g;
      #pragma unroll
      for (int t = 0; t < 4; ++t) {
        float4 qv = *(const float4*)(qp + (16 * t + l15) * 96);
        float4 kv = *(const float4*)(kp + (16 * t + l15) * 96);
        v4s a; a[0] = (short)f2b(qv.x * QS); a[1] = (short)f2b(qv.y * QS);
        a[2] = (short)f2b(qv.z * QS); a[3] = (short)f2b(qv.w * QS);
        aq[t] = a;
        v4s b; b[0] = (short)f2b(kv.x); b[1] = (short)f2b(kv.y);
        b[2] = (short)f2b(kv.z); b[3] = (short)f2b(kv.w);
        bk[t] = b;
      }
    }
    __syncthreads();                             // sM (and sB, first iter) staged

    // ---- fused attention: per row-tile, serial ct: QK^T -> exp2 -> bf16 pa
    //      (unnormalized); after PV scale O by r (P linear in V) ----
    const float* qr = gQ + base + 16 * wave + l15;   // residual column

    #pragma unroll
    for (int rt = 0; rt < 4; ++rt) {
      float s = 0.f;
      v4s pa[4];
      #pragma unroll
      for (int ct = 0; ct < 4; ++ct) {
        ushort4 u = *(const ushort4*)&sM[(16 * rt + l15) * SMS + 16 * ct + 4 * g];
        const int b0 = bb + 30 * (rt - ct);
        v4f acc = {bh[b0 - 0] + b2f(u.x), bh[b0 - 1] + b2f(u.y),
                   bh[b0 - 2] + b2f(u.z), bh[b0 - 3] + b2f(u.w)};
        acc = MFMA16(bk[ct], aq[rt], acc);
        float e0 = exp2f(acc[0]);
        float e1 = exp2f(acc[1]);
        float e2 = exp2f(acc[2]);
        float e3 = exp2f(acc[3]);
        s += (e0 + e1) + (e2 + e3);
        v4s t;
        t[0] = (short)f2b(e0); t[1] = (short)f2b(e1);
        t[2] = (short)f2b(e2); t[3] = (short)f2b(e3);
        pa[ct] = t;
      }
      s += __shfl_xor(s, 16, 64);
      s += __shfl_xor(s, 32, 64);
      const float r = __builtin_amdgcn_rcpf(s);  // per row 16rt+l15

      v4f oa = {0.f, 0.f, 0.f, 0.f};
      #pragma unroll
      for (int ct = 0; ct < 4; ++ct) oa = MFMA16(pa[ct], vf[ct], oa);

      // O row = 16rt+4g+rg needs r from lane with l15 == 4g+rg
      #pragma unroll
      for (int rg = 0; rg < 4; ++rg) {
        const float rr = __shfl(r, 4 * g + rg, 64);
        const int row = 16 * rt + 4 * g + rg;
        sX[row * SXS + 16 * wave + l15] = f2b(oa[rg] * rr + 0.25f * qr[row * 96]);
      }
    }
    __syncthreads();

    // ---- LN partials: row = lane, strip = head ----
    {
      const ushort* xr = &sX[lane * SXS + 16 * wave];
      float s1 = 0.f, s2 = 0.f;
      #pragma unroll
      for (int i = 0; i < 4; ++i) {
        ushort4 u = *(const ushort4*)&xr[i * 4];
        float x0 = b2f(u.x), x1 = b2f(u.y), x2 = b2f(u.z), x3 = b2f(u.w);
        s1 += x0 + x1 + x2 + x3;
        s2 += x0 * x0 + x1 * x1 + x2 * x2 + x3 * x3;
      }
      sPS[lane * 13 + 2 * wave + 0] = s1;
      sPS[lane * 13 + 2 * wave + 1] = s2;
    }

    // ---- W fragments + proj bias (issued here; complete during LN) ----
    v4s wfr[6];
    #pragma unroll
    for (int kk = 0; kk < 6; ++kk) {
      float4 wv = *(const float4*)(gW + oc * 96 + kk * 16 + 4 * g);
      v4s t; t[0] = (short)f2b(wv.x); t[1] = (short)f2b(wv.y);
      t[2] = (short)f2b(wv.z); t[3] = (short)f2b(wv.w);
      wfr[kk] = t;
    }
    const float pb = gPb[oc];
    __syncthreads();

    // ---- LN normalize (strip re-read from LDS, in-place) ----
    {
      float s1 = 0.f, s2 = 0.f;
      #pragma unroll
      for (int t = 0; t < 6; ++t) {
        s1 += sPS[lane * 13 + 2 * t];
        s2 += sPS[lane * 13 + 2 * t + 1];
      }
      const float mu  = s1 * (1.f / 96.f);
      const float var = s2 * (1.f / 96.f) - mu * mu;
      const float rsig = __builtin_amdgcn_rsqf(var + 1e-5f);
      const float* gp = gGa + 16 * wave;
      const float* bp = gBe + 16 * wave;
      ushort* xr = &sX[lane * SXS + 16 * wave];
      #pragma unroll
      for (int i = 0; i < 4; ++i) {
        ushort4 u = *(const ushort4*)&xr[i * 4];
        ushort4 o;
        o.x = f2b((b2f(u.x) - mu) * rsig * gp[4 * i + 0] + bp[4 * i + 0]);
        o.y = f2b((b2f(u.y) - mu) * rsig * gp[4 * i + 1] + bp[4 * i + 1]);
        o.z = f2b((b2f(u.z) - mu) * rsig * gp[4 * i + 2] + bp[4 * i + 2]);
        o.w = f2b((b2f(u.w) - mu) * rsig * gp[4 * i + 3] + bp[4 * i + 3]);
        *(ushort4*)&xr[i * 4] = o;
      }
    }
    __syncthreads();

    // ---- projection: Y = Xn @ W^T + b ----
    v4f ya[4];
    #pragma unroll
    for (int mt = 0; mt < 4; ++mt) { v4f z = {0.f, 0.f, 0.f, 0.f}; ya[mt] = z; }
    #pragma unroll
    for (int kk = 0; kk < 6; ++kk)
      #pragma unroll
      for (int mt = 0; mt < 4; ++mt) {
        v4s xa = *(const v4s*)&sX[(16 * mt + l15) * SXS + 16 * kk + 4 * g];
        ya[mt] = MFMA16(xa, wfr[kk], ya[mt]);
      }

    // ---- staged coalesced output: two 32-row halves through LDS ----
    __syncthreads();                     // all proj LDS reads done
    float* sY = (float*)sX;              // [32][SXS] fp32 = 12800 B
    float4* o4 = (float4*)(gO + base);
    #pragma unroll
    for (int mt = 0; mt < 2; ++mt)
      #pragma unroll
      for (int rg = 0; rg < 4; ++rg)
        sY[(16 * mt + 4 * g + rg) * SXS + oc] = ya[mt][rg] + pb;
    __syncthreads();
    #pragma unroll
    for (int i = 0; i < 2; ++i)
      o4[tid + i * 384] = *(const float4*)&sY[(r0 + 16 * i) * SXS + c0 * 4];
    __syncthreads();
    #pragma unroll
    for (int mt = 2; mt < 4; ++mt)
      #pragma unroll
      for (int rg = 0; rg < 4; ++rg)
        sY[(16 * (mt - 2) + 4 * g + rg) * SXS + oc] = ya[mt][rg] + pb;
    __syncthreads();
    #pragma unroll
    for (int i = 0; i < 2; ++i)
      o4[768 + tid + i * 384] = *(const float4*)&sY[(r0 + 16 * i) * SXS + c0 * 4];
    __syncthreads();                     // sY reads done before next window's sX
  }
}

extern "C" void kernel_launch(void* const* d_in, const int* in_sizes, int n_in,
                              void* d_out, int out_size, void* d_ws, size_t ws_size,
                              hipStream_t stream) {
  (void)in_sizes; (void)n_in; (void)out_size; (void)d_ws; (void)ws_size;
  winattn_kernel<<<dim3(GRID), dim3(384), 0, stream>>>(
      (const float*)d_in[0], (const float*)d_in[1], (const float*)d_in[2],
      (const float*)d_in[3], (const float*)d_in[4], (const float*)d_in[5],
      (const float*)d_in[6], (const float*)d_in[7], (const float*)d_in[8],
      (float*)d_out);
}

// Round 16
// 174.159 us; speedup vs baseline: 1.6051x; 1.5562x over previous
//
#include <hip/hip_runtime.h>
#include <hip/hip_bf16.h>

// DiagWinAttention: nw=4096, N=64 tokens, E=96 = 6 heads x 16. fp32 I/O.
// R16 = the R9 body (proven leanest: 44 VGPR no-spill at cap 102) in a
// 768-thread shell: 12 waves = 2 windows side-by-side. Rationale: measured
// residency is ~1.75 BLOCKS/CU regardless of block size (R5/R7/R14), so
// doubling the block doubles resident waves (R7 hit 65% occ). R7/R8 lost
// the gain to spill under (768,6)'s ~85-reg cap; (768,5) keeps the SAME
// cap as the proven (384,5) config. Tripwire: WRITE_SIZE == 98304 KB.

typedef short v4s __attribute__((ext_vector_type(4)));
typedef float v4f __attribute__((ext_vector_type(4)));

#define MFMA16(A, B, C) __builtin_amdgcn_mfma_f32_16x16x16bf16_1k(A, B, C, 0, 0, 0)

static __device__ __forceinline__ ushort f2b(float x) {
  union { __hip_bfloat16 h; ushort u; } c; c.h = __float2bfloat16(x); return c.u;
}
static __device__ __forceinline__ float b2f(ushort u) {
  union { ushort u; __hip_bfloat16 h; } c; c.u = u; return __bfloat162float(c.h);
}

#define SMS 68      // mask LDS row stride (bf16)
#define SXS 100     // X row stride (bf16); fp32 Y stride in tail
#define SBS 228     // bias table per-head stride (fp32)
#define LOG2E 1.4426950408889634f

__global__ __launch_bounds__(768, 5)
void winattn_kernel(const float* __restrict__ gQ, const float* __restrict__ gK,
                    const float* __restrict__ gV, const float* __restrict__ gM,
                    const float* __restrict__ gBT, const float* __restrict__ gGa,
                    const float* __restrict__ gBe, const float* __restrict__ gW,
                    const float* __restrict__ gPb, float* __restrict__ gO)
{
  __shared__ __align__(16) ushort sM[2][64 * SMS]; // 17408 B mask*log2e
  __shared__ __align__(16) ushort sX[2][64 * SXS]; // 25600 B X -> Xn -> fp32 Y
  __shared__ float sB[6 * SBS];                    //  5472 B bias tables*log2e
  __shared__ float sPS[2][64 * 13];                //  6656 B LN partials
  // total 55136 B -> 2 blocks/CU static

  const int tid  = threadIdx.x;
  const int wave = tid >> 6;           // 0..11
  const int win  = wave >= 6;          // window half
  const int hw   = wave - 6 * win;     // head 0..5
  const int lane = tid & 63;
  const int l15  = lane & 15;
  const int g    = lane >> 4;
  const int ctid = tid - 384 * win;    // 0..383 within window group
  const size_t base = ((size_t)blockIdx.x * 2 + win) * 6144;

  // ---- mask -> LDS (bf16, * log2e); each window's 384 threads stage theirs ----
  {
    const float4* m4 = (const float4*)(gM + ((size_t)blockIdx.x * 2 + win) * 4096);
    ushort* sMw = sM[win];
    #pragma unroll
    for (int i = 0; i < 3; ++i) {
      const int idx = ctid + i * 384;
      if (idx < 1024) {
        const int r = idx >> 4, cc = (idx & 15) * 4;
        float4 a = m4[idx];
        ushort4 u;
        u.x = f2b(a.x * LOG2E); u.y = f2b(a.y * LOG2E);
        u.z = f2b(a.z * LOG2E); u.w = f2b(a.w * LOG2E);
        *(ushort4*)&sMw[r * SMS + cc] = u;
      }
    }
  }
  // ---- bias table -> LDS (fp32, * log2e, per-head layout); all 768 threads ----
  for (int i = tid; i < 1350; i += 768) {
    const int idx = i / 6, h = i - 6 * idx;
    sB[h * SBS + idx] = gBT[i] * LOG2E;
  }

  // ---- V fragments (B-operand): vf[kk] reg j = V[16kk+4g+j][16*hw+l15] ----
  v4s vf[4];
  {
    const float* vp = gV + base + 16 * hw + l15;
    #pragma unroll
    for (int kk = 0; kk < 4; ++kk) {
      float a0 = vp[(16 * kk + 4 * g + 0) * 96];
      float a1 = vp[(16 * kk + 4 * g + 1) * 96];
      float a2 = vp[(16 * kk + 4 * g + 2) * 96];
      float a3 = vp[(16 * kk + 4 * g + 3) * 96];
      v4s t; t[0] = (short)f2b(a0); t[1] = (short)f2b(a1);
      t[2] = (short)f2b(a2); t[3] = (short)f2b(a3);
      vf[kk] = t;
    }
  }

  // ---- Q,K fragments direct from global (A-operand rows) ----
  v4s aq[4], bk[4];
  {
    const float QS = 0.25f * LOG2E;              // scale * log2e folded into Q
    const float* qp = gQ + base + 16 * hw + 4 * g;
    const float* kp = gK + base + 16 * hw + 4 * g;
    #pragma unroll
    for (int t = 0; t < 4; ++t) {
      float4 qv = *(const float4*)(qp + (16 * t + l15) * 96);
      float4 kv = *(const float4*)(kp + (16 * t + l15) * 96);
      v4s a; a[0] = (short)f2b(qv.x * QS); a[1] = (short)f2b(qv.y * QS);
      a[2] = (short)f2b(qv.z * QS); a[3] = (short)f2b(qv.w * QS);
      aq[t] = a;
      v4s b; b[0] = (short)f2b(kv.x); b[1] = (short)f2b(kv.y);
      b[2] = (short)f2b(kv.z); b[3] = (short)f2b(kv.w);
      bk[t] = b;
    }
  }
  __syncthreads();                               // sM/sB staged

  // ---- fused attention (R9 body): per row-tile, serial ct: QK^T -> exp2 ->
  //      bf16 pa (unnormalized); after PV scale O by r (P linear in V) ----
  const float* bh = &sB[hw * SBS];
  const int bb = ((l15 >> 3) - (g >> 1)) * 15 + (l15 & 7) - 4 * (g & 1) + 112;
  const float* qr = gQ + base + 16 * hw + l15;   // residual column
  const ushort* sMw = sM[win];
  ushort* sXw = sX[win];

  #pragma unroll
  for (int rt = 0; rt < 4; ++rt) {
    float s = 0.f;
    v4s pa[4];
    #pragma unroll
    for (int ct = 0; ct < 4; ++ct) {
      ushort4 u = *(const ushort4*)&sMw[(16 * rt + l15) * SMS + 16 * ct + 4 * g];
      const int b0 = bb + 30 * (rt - ct);
      v4f acc = {bh[b0 - 0] + b2f(u.x), bh[b0 - 1] + b2f(u.y),
                 bh[b0 - 2] + b2f(u.z), bh[b0 - 3] + b2f(u.w)};
      acc = MFMA16(bk[ct], aq[rt], acc);
      float e0 = exp2f(acc[0]);
      float e1 = exp2f(acc[1]);
      float e2 = exp2f(acc[2]);
      float e3 = exp2f(acc[3]);
      s += (e0 + e1) + (e2 + e3);
      v4s t;
      t[0] = (short)f2b(e0); t[1] = (short)f2b(e1);
      t[2] = (short)f2b(e2); t[3] = (short)f2b(e3);
      pa[ct] = t;
    }
    s += __shfl_xor(s, 16, 64);
    s += __shfl_xor(s, 32, 64);
    const float r = __builtin_amdgcn_rcpf(s);    // per row 16rt+l15

    v4f oa = {0.f, 0.f, 0.f, 0.f};
    #pragma unroll
    for (int ct = 0; ct < 4; ++ct) oa = MFMA16(pa[ct], vf[ct], oa);

    // O row = 16rt+4g+rg needs r from lane with l15 == 4g+rg
    #pragma unroll
    for (int rg = 0; rg < 4; ++rg) {
      const float rr = __shfl(r, 4 * g + rg, 64);
      const int row = 16 * rt + 4 * g + rg;
      sXw[row * SXS + 16 * hw + l15] = f2b(oa[rg] * rr + 0.25f * qr[row * 96]);
    }
  }
  __syncthreads();

  // ---- LN partials: row = lane, strip = head ----
  float* sPSw = sPS[win];
  {
    const ushort* xr = &sXw[lane * SXS + 16 * hw];
    float s1 = 0.f, s2 = 0.f;
    #pragma unroll
    for (int i = 0; i < 4; ++i) {
      ushort4 u = *(const ushort4*)&xr[i * 4];
      float x0 = b2f(u.x), x1 = b2f(u.y), x2 = b2f(u.z), x3 = b2f(u.w);
      s1 += x0 + x1 + x2 + x3;
      s2 += x0 * x0 + x1 * x1 + x2 * x2 + x3 * x3;
    }
    sPSw[lane * 13 + 2 * hw + 0] = s1;
    sPSw[lane * 13 + 2 * hw + 1] = s2;
  }

  // ---- W fragments + proj bias (issued here; complete during LN) ----
  const int oc = 16 * hw + l15;
  v4s wfr[6];
  #pragma unroll
  for (int kk = 0; kk < 6; ++kk) {
    float4 wv = *(const float4*)(gW + oc * 96 + kk * 16 + 4 * g);
    v4s t; t[0] = (short)f2b(wv.x); t[1] = (short)f2b(wv.y);
    t[2] = (short)f2b(wv.z); t[3] = (short)f2b(wv.w);
    wfr[kk] = t;
  }
  const float pb = gPb[oc];
  __syncthreads();

  // ---- LN normalize (strip re-read from LDS, in-place) ----
  {
    float s1 = 0.f, s2 = 0.f;
    #pragma unroll
    for (int t = 0; t < 6; ++t) {
      s1 += sPSw[lane * 13 + 2 * t];
      s2 += sPSw[lane * 13 + 2 * t + 1];
    }
    const float mu  = s1 * (1.f / 96.f);
    const float var = s2 * (1.f / 96.f) - mu * mu;
    const float rsig = __builtin_amdgcn_rsqf(var + 1e-5f);
    const float* gp = gGa + 16 * hw;
    const float* bp = gBe + 16 * hw;
    ushort* xr = &sXw[lane * SXS + 16 * hw];
    #pragma unroll
    for (int i = 0; i < 4; ++i) {
      ushort4 u = *(const ushort4*)&xr[i * 4];
      ushort4 o;
      o.x = f2b((b2f(u.x) - mu) * rsig * gp[4 * i + 0] + bp[4 * i + 0]);
      o.y = f2b((b2f(u.y) - mu) * rsig * gp[4 * i + 1] + bp[4 * i + 1]);
      o.z = f2b((b2f(u.z) - mu) * rsig * gp[4 * i + 2] + bp[4 * i + 2]);
      o.w = f2b((b2f(u.w) - mu) * rsig * gp[4 * i + 3] + bp[4 * i + 3]);
      *(ushort4*)&xr[i * 4] = o;
    }
  }
  __syncthreads();

  // ---- projection: Y = Xn @ W^T + b ----
  v4f ya[4];
  #pragma unroll
  for (int mt = 0; mt < 4; ++mt) { v4f z = {0.f, 0.f, 0.f, 0.f}; ya[mt] = z; }
  #pragma unroll
  for (int kk = 0; kk < 6; ++kk)
    #pragma unroll
    for (int mt = 0; mt < 4; ++mt) {
      v4s xa = *(const v4s*)&sXw[(16 * mt + l15) * SXS + 16 * kk + 4 * g];
      ya[mt] = MFMA16(xa, wfr[kk], ya[mt]);
    }

  // ---- staged coalesced output: two 32-row halves through LDS (stride 100) ----
  __syncthreads();                       // all proj LDS reads done
  float* sY = (float*)sXw;               // [32][SXS] fp32 = 12800 B
  float4* o4 = (float4*)(gO + base);
  const int r0 = ctid / 24, c0 = ctid % 24;    // 384 = 16 rows x 24 float4
  #pragma unroll
  for (int mt = 0; mt < 2; ++mt)
    #pragma unroll
    for (int rg = 0; rg < 4; ++rg)
      sY[(16 * mt + 4 * g + rg) * SXS + oc] = ya[mt][rg] + pb;
  __syncthreads();
  #pragma unroll
  for (int i = 0; i < 2; ++i)
    o4[ctid + i * 384] = *(const float4*)&sY[(r0 + 16 * i) * SXS + c0 * 4];
  __syncthreads();
  #pragma unroll
  for (int mt = 2; mt < 4; ++mt)
    #pragma unroll
    for (int rg = 0; rg < 4; ++rg)
      sY[(16 * (mt - 2) + 4 * g + rg) * SXS + oc] = ya[mt][rg] + pb;
  __syncthreads();
  #pragma unroll
  for (int i = 0; i < 2; ++i)
    o4[768 + ctid + i * 384] = *(const float4*)&sY[(r0 + 16 * i) * SXS + c0 * 4];
}

extern "C" void kernel_launch(void* const* d_in, const int* in_sizes, int n_in,
                              void* d_out, int out_size, void* d_ws, size_t ws_size,
                              hipStream_t stream) {
  (void)in_sizes; (void)n_in; (void)out_size; (void)d_ws; (void)ws_size;
  winattn_kernel<<<dim3(2048), dim3(768), 0, stream>>>(
      (const float*)d_in[0], (const float*)d_in[1], (const float*)d_in[2],
      (const float*)d_in[3], (const float*)d_in[4], (const float*)d_in[5],
      (const float*)d_in[6], (const float*)d_in[7], (const float*)d_in[8],
      (float*)d_out);
}